// Round 13
// baseline (162.877 us; speedup 1.0000x reference)
//
#include <hip/hip_runtime.h>
#include <hip/hip_bf16.h>

// Problem constants (B=2, S=2048, E=1024, H=16, d=64)
#define BB 2
#define SS 2048
#define EE 1024
#define HH 16
#define DD 64

using bfrag  = __attribute__((ext_vector_type(8))) short;  // 8 bf16 (4 VGPRs)
using bfrag4 = __attribute__((ext_vector_type(4))) short;  // 4 bf16 (2 VGPRs)
using ffrag  = __attribute__((ext_vector_type(4))) float;  // 4 fp32 accum
using uint2v = __attribute__((ext_vector_type(2))) uint;
using uint4v = __attribute__((ext_vector_type(4))) uint;

#define MFMA32(A, B, C) __builtin_amdgcn_mfma_f32_16x16x32_bf16(A, B, C, 0, 0, 0)

static __device__ __forceinline__ ushort f2bf(float f) {
  __hip_bfloat16 h = __float2bfloat16(f);
  return *reinterpret_cast<ushort*>(&h);
}

// Pack two fp32 -> two bf16 (round-half-up) in 3 VALU ops via v_perm_b32.
static __device__ __forceinline__ uint pack_bf2(float lo, float hi) {
  uint a = __float_as_uint(lo) + 0x8000u;
  uint b = __float_as_uint(hi) + 0x8000u;
  return __builtin_amdgcn_perm(b, a, 0x07060302u);
}

// Async global->LDS, 16 B per lane. LDS dest = wave-uniform base + lane*16.
static __device__ __forceinline__ void gl_lds16(const ushort* g, ushort* l) {
  __builtin_amdgcn_global_load_lds(
      (const __attribute__((address_space(1))) void*)g,
      (__attribute__((address_space(3))) void*)l, 16, 0, 0);
}

// -------------------------------------------------------------------------
// Fused prep: x fp32->bf16 cast (blocks 0..4095) + weight transpose+cast
// (blocks 4096..6271): wq -> wqkvT[0:1024), wo -> woT, wk -> wqkvT[1024:1088),
// wv -> wqkvT[1088:1152). One launch instead of five.
// -------------------------------------------------------------------------
__global__ __launch_bounds__(256) void prep(
    const float* __restrict__ x, const float* __restrict__ wq,
    const float* __restrict__ wk, const float* __restrict__ wv,
    const float* __restrict__ wo, ushort* __restrict__ xb,
    ushort* __restrict__ wqkvT, ushort* __restrict__ woT) {
  __shared__ float t[32][33];
  int id = blockIdx.x;
  if (id < 4096) {  // cast path: 4096*256*4 = 4M elements
    int i = id * 256 + threadIdx.x;
    float4 v = ((const float4*)x)[i];
    ushort4 u = { f2bf(v.x), f2bf(v.y), f2bf(v.z), f2bf(v.w) };
    ((ushort4*)xb)[i] = u;
    return;
  }
  id -= 4096;
  const float* src;
  ushort* dst;
  int N, bx, by;
  if (id < 1024)      { src = wq; dst = wqkvT;                      N = 1024; bx = id & 31;          by = id >> 5; }
  else if (id < 2048) { src = wo; dst = woT;                        N = 1024; bx = (id - 1024) & 31; by = (id - 1024) >> 5; }
  else if (id < 2112) { src = wk; dst = wqkvT + (size_t)1024 * 1024; N = 64;  bx = (id - 2048) & 1;  by = (id - 2048) >> 1; }
  else                { src = wv; dst = wqkvT + (size_t)1088 * 1024; N = 64;  bx = (id - 2112) & 1;  by = (id - 2112) >> 1; }
  const int k0 = by * 32, n0 = bx * 32;
  const int tx = threadIdx.x & 31, ty = threadIdx.x >> 5;  // 32x8
  #pragma unroll
  for (int i = 0; i < 32; i += 8)
    t[ty + i][tx] = src[(size_t)(k0 + ty + i) * N + n0 + tx];
  __syncthreads();
  #pragma unroll
  for (int i = 0; i < 32; i += 8)
    dst[(size_t)(n0 + ty + i) * 1024 + k0 + tx] = f2bf(t[tx][ty + i]);
}

// -------------------------------------------------------------------------
// bf16 MFMA GEMM, R13: 128(M)x64(N) tile, BK=64, EIGHT waves (wave tile
// 32x32, acc[2][2]) + XCD-aware block swizzle. Mechanism: the GEMM is
// barrier-drain-bound (issue accounting: MFMA ~2%, LDS ~17% busy) at only
// 2.25 waves/SIMD. Subdividing the SAME tile among 8 waves keeps LDS
// (48KB), grid (576/512), DMA count, and barrier count identical while
// doubling resident waves -> 4.5 waves/SIMD to overlap the per-phase
// vmcnt(0) drains. (R3/R7 changed tile=traffic, R6 LDS, R9 VGPR -- all
// regressed; this isolates the TLP variable.)
// Dbuf global_load_lds staging, one barrier/iter. XOR-swizzled 16B chunks.
// QKV=true: Bt = [wq|wk|wv]^T (N=1152). Epilogue per n-tile:
//   col<1024 -> Qb; 1024..1088 -> Kb ([4096x64]); 1088..1152 -> VT
//   (bf16, transposed [B][64][S]) in PV-PERMUTED key order: within each
//   32-key block, pos(t) = ((t>>2)&3)*8 + ((t>>4)&1)*4 + (t&3).
// QKV=false: fp32 out = acc + bias0 (O projection).
// -------------------------------------------------------------------------
template <bool QKV>
__global__ __launch_bounds__(512) void gemm_mfma3(
    const ushort* __restrict__ A, const ushort* __restrict__ Bt,
    const float* __restrict__ bias0, const float* __restrict__ bias1,
    const float* __restrict__ bias2, void* __restrict__ O1,
    ushort* __restrict__ Kb, ushort* __restrict__ VTb,
    int M, int N, int K, float qscale) {
  __shared__ __align__(16) ushort As[2][128 * 64];
  __shared__ __align__(16) ushort Bs[2][64 * 64];
  const int tid = threadIdx.x;
  const int lane = tid & 63;
  const int quad = lane >> 4;
  const int c = lane & 15;
  const int wv = tid >> 6;          // 0..7
  const int wm = (wv & 3) * 32;     // 4 m-strips
  const int wn = (wv >> 2) * 32;    // 2 n-groups

  // XCD-aware swizzle: each XCD gets 4 contiguous m-rows x all n-tiles.
  const int gx = gridDim.x, gy = gridDim.y;
  const int lid = blockIdx.y * gx + blockIdx.x;
  const int xcd = lid & 7;
  const int idx = lid >> 3;
  const int mrow = xcd * (gy >> 3) + idx / gx;
  const int ncol = idx % gx;
  const size_t m0 = (size_t)mrow * 128;
  const size_t n0 = (size_t)ncol * 64;

  const int srow = lane >> 3;             // row within 8-row slab
  const int sck = (lane & 7) ^ srow;      // swizzled chunk (k) within row

  ffrag zero = {0.f, 0.f, 0.f, 0.f};
  ffrag acc[2][2];
  #pragma unroll
  for (int mt = 0; mt < 2; ++mt)
    #pragma unroll
    for (int nt = 0; nt < 2; ++nt) acc[mt][nt] = zero;

  const int NK = K >> 6;
  #pragma unroll
  for (int i = 0; i < 2; ++i) {   // A: 16 slabs over 8 waves = 2 each
    int ia = wv * 2 + i;
    gl_lds16(&A[(m0 + ia * 8 + srow) * (size_t)K + sck * 8], &As[0][ia * 512]);
  }
  {                               // B: 8 slabs over 8 waves = 1 each
    int ib = wv;
    gl_lds16(&Bt[(n0 + ib * 8 + srow) * (size_t)K + sck * 8], &Bs[0][ib * 512]);
  }
  __syncthreads();

  for (int ki = 0; ki < NK; ++ki) {
    const int buf = ki & 1;
    if (ki + 1 < NK) {
      int k0 = (ki + 1) << 6;
      #pragma unroll
      for (int i = 0; i < 2; ++i) {
        int ia = wv * 2 + i;
        gl_lds16(&A[(m0 + ia * 8 + srow) * (size_t)K + k0 + sck * 8],
                 &As[buf ^ 1][ia * 512]);
      }
      {
        int ib = wv;
        gl_lds16(&Bt[(n0 + ib * 8 + srow) * (size_t)K + k0 + sck * 8],
                 &Bs[buf ^ 1][ib * 512]);
      }
    }
    #pragma unroll
    for (int ks = 0; ks < 2; ++ks) {
      bfrag af[2], bf[2];
      #pragma unroll
      for (int mt = 0; mt < 2; ++mt) {
        int ra = wm + mt * 16 + c;
        af[mt] = *(const bfrag*)&As[buf][(ra * 8 + ((ks * 4 + quad) ^ (ra & 7))) * 8];
      }
      #pragma unroll
      for (int nt = 0; nt < 2; ++nt) {
        int rb = wn + nt * 16 + c;
        bf[nt] = *(const bfrag*)&Bs[buf][(rb * 8 + ((ks * 4 + quad) ^ (rb & 7))) * 8];
      }
      #pragma unroll
      for (int mt = 0; mt < 2; ++mt)
        #pragma unroll
        for (int nt = 0; nt < 2; ++nt)
          acc[mt][nt] = MFMA32(af[mt], bf[nt], acc[mt][nt]);
    }
    __syncthreads();
  }

  #pragma unroll
  for (int nt = 0; nt < 2; ++nt) {
    const int colb = (int)n0 + wn + nt * 16;  // multiple of 16
    if (QKV) {
      if (colb < 1024) {         // Q block (pre-scaled bf16)
        float bb = bias0[colb + c];
        ushort* dst = (ushort*)O1 + colb;
        #pragma unroll
        for (int mt = 0; mt < 2; ++mt)
          #pragma unroll
          for (int r = 0; r < 4; ++r) {
            size_t row = m0 + wm + mt * 16 + quad * 4 + r;
            dst[row * 1024 + c] = f2bf((acc[mt][nt][r] + bb) * qscale);
          }
      } else if (colb < 1088) {  // K block -> Kb [4096 x 64]
        float bb = bias1[colb - 1024 + c];
        ushort* dst = Kb + (colb - 1024);
        #pragma unroll
        for (int mt = 0; mt < 2; ++mt)
          #pragma unroll
          for (int r = 0; r < 4; ++r) {
            size_t row = m0 + wm + mt * 16 + quad * 4 + r;
            dst[row * 64 + c] = f2bf(acc[mt][nt][r] + bb);
          }
      } else {                   // V block -> VT permuted [B][64][S]
        int d = colb - 1088 + c;
        float bb = bias2[colb - 1088 + c];
        int bidx = (int)(m0 >> 11);
        ushort* dstv = VTb + ((size_t)(bidx * 64 + d)) * SS;
        #pragma unroll
        for (int mt = 0; mt < 2; ++mt) {
          int sb = (int)(m0 & 2047) + wm + mt * 16 + quad * 4;  // mult of 4
          // PV-permuted position within the 32-key block (4 consecutive)
          int col = (sb & ~31) + ((sb >> 2) & 3) * 8 + ((sb >> 4) & 1) * 4;
          uint2v u;
          u.x = pack_bf2(acc[mt][nt][0] + bb, acc[mt][nt][1] + bb);
          u.y = pack_bf2(acc[mt][nt][2] + bb, acc[mt][nt][3] + bb);
          *(uint2v*)&dstv[col] = u;
        }
      }
    } else {
      float bb = bias0[colb + c];
      float* dst = (float*)O1;
      #pragma unroll
      for (int mt = 0; mt < 2; ++mt)
        #pragma unroll
        for (int r = 0; r < 4; ++r) {
          size_t row = m0 + wm + mt * 16 + quad * 4 + r;
          dst[row * (size_t)N + colb + c] = acc[mt][nt][r] + bb;
        }
    }
  }
}

// -------------------------------------------------------------------------
// MQA attention v15 (unchanged from R12: 49.5 us, conflicts 0, VGPR 56).
// v12 structure + PV via K=32 MFMA on permuted keys: two 16-key QK^T
// tiles' S^T fragments concatenate into a 16x16x32 B-frag (k = quad*8+j).
// Per 64-key iter: QK 16 MFMA32 + PV 16 MFMA32 + 4 lsum MFMA32; V reads
// 8 b128; all staging via gl_lds16 DMA (linear dest, chunk-swizzled
// GLOBAL source: chunk' = chunk ^ (d&7), <=2-way on read = free).
// Block = 8 waves (512 thr), 128 q; waves 0-3 keys [0,1024), waves 4-7
// keys [1024,2048); each wave owns 32 q (2 q-tiles). 512 blocks.
// Combine halves via retired LDS; normalize by 1/(ls_lo+ls_hi).
// -------------------------------------------------------------------------
__global__ __launch_bounds__(512) void mqa_attn15(
    const ushort* __restrict__ Q, const ushort* __restrict__ Kg,
    const ushort* __restrict__ VT, ushort* __restrict__ A2) {
  __shared__ __align__(16) ushort Kt[2][2][4096];  // [half][buf][64k x 64d]
  __shared__ __align__(16) ushort Vt[2][2][4096];  // [half][buf][64d x 64pos, chunk-swz]
  const int tid = threadIdx.x;
  const int lane = tid & 63;
  const int quad = lane >> 4;
  const int c = lane & 15;
  const int wv = tid >> 6;        // 0..7
  const int half = wv >> 2;       // 0: keys [0,1024), 1: [1024,2048)
  const int lw = wv & 3;          // wave-within-half, owns q-tiles lw*2+{0,1}
  const int bid = blockIdx.x;     // [0, 512)
  const int b = bid >> 8;
  const int r = bid & 255;
  const int h = r >> 4;           // 16 blocks per head
  const int s0 = (r & 15) << 7;   // 128 queries per block

  const int srow = lane >> 3;            // row within 8-row slab
  const int sck = (lane & 7) ^ srow;     // swizzled chunk within row (K staging)

  ffrag zero = {0.f, 0.f, 0.f, 0.f};
  bfrag ones8;
  #pragma unroll
  for (int i = 0; i < 8; ++i) ones8[i] = (short)16256;  // bf16 1.0

  // Q b-frags: 2 q-tiles x 2 d-halves, held for the whole key loop
  bfrag aq[2][2];
  #pragma unroll
  for (int mt = 0; mt < 2; ++mt) {
    const ushort* qp =
        Q + ((size_t)(b * SS) + s0 + lw * 32 + mt * 16 + c) * EE + h * 64 + quad * 8;
    aq[mt][0] = *(const bfrag*)qp;
    aq[mt][1] = *(const bfrag*)(qp + 32);
  }

  ffrag o[2][4];   // O^T accum: [q-tile][d-tile]
  #pragma unroll
  for (int mt = 0; mt < 2; ++mt)
    #pragma unroll
    for (int nt = 0; nt < 4; ++nt) o[mt][nt] = zero;
  ffrag ls[2] = {zero, zero};

  const int koff = half << 10;    // key offset of this half
  const ushort* Kbase = Kg + (size_t)b * SS * 64;
  const ushort* Vbase = VT + (size_t)b * 64 * SS;
  const int i0 = lw * 2, i1 = lw * 2 + 1;
  const int r0 = i0 * 8 + srow, r1 = i1 * 8 + srow;  // key-rows staged (K)

  // V DMA geometry: lane -> (row-in-slab = lane>>3, chunk = lane&7);
  // global source pre-swizzled: chunk' = chunk ^ (d&7); dest linear.
  const int vd0 = lw * 16 + (lane >> 3);       // d row, DMA 0
  const int vd1 = vd0 + 8;                     // d row, DMA 1
  const ushort* vsrc0 = Vbase + (size_t)vd0 * SS + (((lane & 7) ^ (vd0 & 7)) * 8);
  const ushort* vsrc1 = Vbase + (size_t)vd1 * SS + (((lane & 7) ^ (vd1 & 7)) * 8);

  // ---- prologue: stage tile 0 (K + V all via DMA)
  gl_lds16(Kbase + (size_t)(koff + r0) * 64 + sck * 8, &Kt[half][0][i0 * 512]);
  gl_lds16(Kbase + (size_t)(koff + r1) * 64 + sck * 8, &Kt[half][0][i1 * 512]);
  gl_lds16(vsrc0 + koff, &Vt[half][0][(lw * 16) * 64]);
  gl_lds16(vsrc1 + koff, &Vt[half][0][(lw * 16 + 8) * 64]);
  __syncthreads();

  for (int it = 0; it < 16; ++it) {
    const int buf = it & 1;
    if (it + 1 < 16) {  // early-issue next K/V tile (all DMA)
      int kb = koff + ((it + 1) << 6);
      gl_lds16(Kbase + (size_t)(kb + r0) * 64 + sck * 8, &Kt[half][buf ^ 1][i0 * 512]);
      gl_lds16(Kbase + (size_t)(kb + r1) * 64 + sck * 8, &Kt[half][buf ^ 1][i1 * 512]);
      gl_lds16(vsrc0 + kb, &Vt[half][buf ^ 1][(lw * 16) * 64]);
      gl_lds16(vsrc1 + kb, &Vt[half][buf ^ 1][(lw * 16 + 8) * 64]);
    }

    #pragma unroll
    for (int p = 0; p < 2; ++p) {     // 32-key pair-tile
      uint2v uu[2][2];                // [a (16-key subtile)][mt]
      #pragma unroll
      for (int a = 0; a < 2; ++a) {
        const int key = (p * 2 + a) * 16 + c;   // A-frag row (key) for S^T
        const int k7 = key & 7;
        bfrag kf0 = *(const bfrag*)&Kt[half][buf][(key * 8 + (quad ^ k7)) * 8];
        bfrag kf1 = *(const bfrag*)&Kt[half][buf][(key * 8 + ((quad + 4) ^ k7)) * 8];
        #pragma unroll
        for (int mt = 0; mt < 2; ++mt) {
          ffrag st = MFMA32(kf0, aq[mt][0], zero);
          st = MFMA32(kf1, aq[mt][1], st);
          // lane holds S^T[key=(2p+a)*16+quad*4+j][q=mt*16+c], j=0..3
          uu[a][mt].x = pack_bf2(__builtin_amdgcn_exp2f(st[0]),
                                 __builtin_amdgcn_exp2f(st[1]));
          uu[a][mt].y = pack_bf2(__builtin_amdgcn_exp2f(st[2]),
                                 __builtin_amdgcn_exp2f(st[3]));
        }
      }
      // concat -> K=32 B-frag: k = quad*8 + (a*4+j) = permuted V position
      bfrag pb8[2];
      #pragma unroll
      for (int mt = 0; mt < 2; ++mt) {
        uint4v w = {uu[0][mt].x, uu[0][mt].y, uu[1][mt].x, uu[1][mt].y};
        pb8[mt] = __builtin_bit_cast(bfrag, w);
      }
      // PV: O^T[d][q] += V^T-frag(K=32) * P-frag(K=32)
      const int ch = p * 4 + quad;    // logical 16B chunk (8 positions)
      #pragma unroll
      for (int nt = 0; nt < 4; ++nt) {
        int d = nt * 16 + c;
        bfrag vf = *(const bfrag*)&Vt[half][buf][d * 64 + ((ch ^ (d & 7)) * 8)];
        #pragma unroll
        for (int mt = 0; mt < 2; ++mt)
          o[mt][nt] = MFMA32(vf, pb8[mt], o[mt][nt]);
      }
      #pragma unroll
      for (int mt = 0; mt < 2; ++mt)
        ls[mt] = MFMA32(ones8, pb8[mt], ls[mt]);
    }
    __syncthreads();
  }

  // ---- combine halves via retired LDS (Kt area: 4 waves x 8 KB; Vt: lsums)
  float* cbuf = (float*)&Kt[0][0][0];
  float* lbuf = (float*)&Vt[0][0][0];
  if (half == 1) {
    float* wb = cbuf + (size_t)lw * 2048;
    #pragma unroll
    for (int mt = 0; mt < 2; ++mt) {
      #pragma unroll
      for (int nt = 0; nt < 4; ++nt)
        *(ffrag*)&wb[(mt * 4 + nt) * 256 + lane * 4] = o[mt][nt];
      lbuf[lw * 128 + mt * 64 + lane] = ls[mt][0];
    }
  }
  __syncthreads();
  if (half == 1) return;

  const float* rb = cbuf + (size_t)lw * 2048;
  #pragma unroll
  for (int mt = 0; mt < 2; ++mt) {
    #pragma unroll
    for (int nt = 0; nt < 4; ++nt) {
      ffrag pp = *(const ffrag*)&rb[(mt * 4 + nt) * 256 + lane * 4];
      o[mt][nt] += pp;
    }
    const float inv = 1.f / (ls[mt][0] + lbuf[lw * 128 + mt * 64 + lane]);
    const int sp = h * 128 + (s0 >> 4) + lw * 2 + mt;
    ushort* orow = A2 + ((size_t)b * SS + sp) * EE;
    #pragma unroll
    for (int nt = 0; nt < 4; ++nt) {
      uint2v u;
      u.x = pack_bf2(o[mt][nt][0] * inv, o[mt][nt][1] * inv);
      u.y = pack_bf2(o[mt][nt][2] * inv, o[mt][nt][3] * inv);
      *(uint2v*)&orow[c * 64 + nt * 16 + quad * 4] = u;
    }
  }
}

extern "C" void kernel_launch(void* const* d_in, const int* in_sizes, int n_in,
                              void* d_out, int out_size, void* d_ws, size_t ws_size,
                              hipStream_t stream) {
  const float* x  = (const float*)d_in[0];
  const float* wq = (const float*)d_in[1];
  const float* bq = (const float*)d_in[2];
  const float* wk = (const float*)d_in[3];
  const float* bk = (const float*)d_in[4];
  const float* wv = (const float*)d_in[5];
  const float* bv = (const float*)d_in[6];
  const float* wo = (const float*)d_in[7];
  const float* bo = (const float*)d_in[8];
  float* out = (float*)d_out;

  // Workspace layout (bytes)
  char* w = (char*)d_ws;
  ushort* xb     = (ushort*)w;  w += (size_t)4096 * 1024 * 2;  // x bf16
  ushort* wqkvT  = (ushort*)w;  w += (size_t)1152 * 1024 * 2;  // [wq|wk|wv]^T
  ushort* woT    = (ushort*)w;  w += (size_t)1024 * 1024 * 2;  // wo^T bf16
  ushort* Qb     = (ushort*)w;  w += (size_t)4096 * 1024 * 2;  // Q' (pre-scaled)
  ushort* Kb     = (ushort*)w;  w += (size_t)4096 * 64 * 2;    // K bf16 [4096x64]
  ushort* VTb    = (ushort*)w;  w += (size_t)BB * 64 * SS * 2; // V^T bf16 (permuted)
  ushort* A2     = (ushort*)w;  w += (size_t)4096 * 1024 * 2;  // attn (scrambled)

  // Prep: x cast + all weight transposes in one launch
  prep<<<6272, 256, 0, stream>>>(x, wq, wk, wv, wo, xb, wqkvT, woT);

  // Fused QKV projection (V written transposed + PV-permuted).
  const float qscale = 0.18033688011112042f;  // log2(e)/8
  gemm_mfma3<true><<<dim3(18, 32), 512, 0, stream>>>(
      xb, wqkvT, bq, bk, bv, Qb, Kb, VTb, 4096, 1152, 1024, qscale);

  // Attention: v15 -- PV via K=32 MFMA on permuted keys, all-DMA staging
  mqa_attn15<<<512, 512, 0, stream>>>(Qb, Kb, VTb, A2);

  // Output projection (fp32 out + bias)
  gemm_mfma3<false><<<dim3(16, 32), 512, 0, stream>>>(
      A2, woT, bo, nullptr, nullptr, out, nullptr, nullptr, 4096, 1024, 1024, 1.0f);
}

// Round 14
// 161.887 us; speedup vs baseline: 1.0061x; 1.0061x over previous
//
#include <hip/hip_runtime.h>
#include <hip/hip_bf16.h>

// Problem constants (B=2, S=2048, E=1024, H=16, d=64)
#define BB 2
#define SS 2048
#define EE 1024
#define HH 16
#define DD 64

using bfrag  = __attribute__((ext_vector_type(8))) short;  // 8 bf16 (4 VGPRs)
using bfrag4 = __attribute__((ext_vector_type(4))) short;  // 4 bf16 (2 VGPRs)
using ffrag  = __attribute__((ext_vector_type(4))) float;  // 4 fp32 accum
using uint2v = __attribute__((ext_vector_type(2))) uint;
using uint4v = __attribute__((ext_vector_type(4))) uint;

#define MFMA32(A, B, C) __builtin_amdgcn_mfma_f32_16x16x32_bf16(A, B, C, 0, 0, 0)

static __device__ __forceinline__ ushort f2bf(float f) {
  __hip_bfloat16 h = __float2bfloat16(f);
  return *reinterpret_cast<ushort*>(&h);
}

// Pack two fp32 -> two bf16 (round-half-up) in 3 VALU ops via v_perm_b32.
static __device__ __forceinline__ uint pack_bf2(float lo, float hi) {
  uint a = __float_as_uint(lo) + 0x8000u;
  uint b = __float_as_uint(hi) + 0x8000u;
  return __builtin_amdgcn_perm(b, a, 0x07060302u);
}

// Async global->LDS, 16 B per lane. LDS dest = wave-uniform base + lane*16.
static __device__ __forceinline__ void gl_lds16(const ushort* g, ushort* l) {
  __builtin_amdgcn_global_load_lds(
      (const __attribute__((address_space(1))) void*)g,
      (__attribute__((address_space(3))) void*)l, 16, 0, 0);
}

// -------------------------------------------------------------------------
// Fused prep: x fp32->bf16 cast (blocks 0..4095) + weight transpose+cast
// (blocks 4096..6271): wq -> wqkvT[0:1024), wo -> woT, wk -> wqkvT[1024:1088),
// wv -> wqkvT[1088:1152). One launch instead of five.
// -------------------------------------------------------------------------
__global__ __launch_bounds__(256) void prep(
    const float* __restrict__ x, const float* __restrict__ wq,
    const float* __restrict__ wk, const float* __restrict__ wv,
    const float* __restrict__ wo, ushort* __restrict__ xb,
    ushort* __restrict__ wqkvT, ushort* __restrict__ woT) {
  __shared__ float t[32][33];
  int id = blockIdx.x;
  if (id < 4096) {  // cast path: 4096*256*4 = 4M elements
    int i = id * 256 + threadIdx.x;
    float4 v = ((const float4*)x)[i];
    ushort4 u = { f2bf(v.x), f2bf(v.y), f2bf(v.z), f2bf(v.w) };
    ((ushort4*)xb)[i] = u;
    return;
  }
  id -= 4096;
  const float* src;
  ushort* dst;
  int N, bx, by;
  if (id < 1024)      { src = wq; dst = wqkvT;                      N = 1024; bx = id & 31;          by = id >> 5; }
  else if (id < 2048) { src = wo; dst = woT;                        N = 1024; bx = (id - 1024) & 31; by = (id - 1024) >> 5; }
  else if (id < 2112) { src = wk; dst = wqkvT + (size_t)1024 * 1024; N = 64;  bx = (id - 2048) & 1;  by = (id - 2048) >> 1; }
  else                { src = wv; dst = wqkvT + (size_t)1088 * 1024; N = 64;  bx = (id - 2112) & 1;  by = (id - 2112) >> 1; }
  const int k0 = by * 32, n0 = bx * 32;
  const int tx = threadIdx.x & 31, ty = threadIdx.x >> 5;  // 32x8
  #pragma unroll
  for (int i = 0; i < 32; i += 8)
    t[ty + i][tx] = src[(size_t)(k0 + ty + i) * N + n0 + tx];
  __syncthreads();
  #pragma unroll
  for (int i = 0; i < 32; i += 8)
    dst[(size_t)(n0 + ty + i) * 1024 + k0 + tx] = f2bf(t[tx][ty + i]);
}

// -------------------------------------------------------------------------
// bf16 MFMA GEMM, 128(M)x64(N) tile, BK=64, 4 waves, wave tile 64x32
// + XCD-aware block swizzle (R12-exact config: session-best measured;
// R13's 8-wave subdivision regressed -5 us -> reverted. Six structural
// variants all within [111,127] us non-attn: this is the plateau point).
// Dbuf global_load_lds staging, one barrier/iter. XOR-swizzled 16B chunks.
// QKV=true: Bt = [wq|wk|wv]^T (N=1152). Epilogue per n-tile:
//   col<1024 -> Qb; 1024..1088 -> Kb ([4096x64]); 1088..1152 -> VT
//   (bf16, transposed [B][64][S]) in PV-PERMUTED key order: within each
//   32-key block, pos(t) = ((t>>2)&3)*8 + ((t>>4)&1)*4 + (t&3), so a
//   lane's S^T fragments from two 16-key QK tiles form a 16x16x32 B-frag.
// QKV=false: fp32 out = acc + bias0 (O projection).
// -------------------------------------------------------------------------
template <bool QKV>
__global__ __launch_bounds__(256) void gemm_mfma3(
    const ushort* __restrict__ A, const ushort* __restrict__ Bt,
    const float* __restrict__ bias0, const float* __restrict__ bias1,
    const float* __restrict__ bias2, void* __restrict__ O1,
    ushort* __restrict__ Kb, ushort* __restrict__ VTb,
    int M, int N, int K, float qscale) {
  __shared__ __align__(16) ushort As[2][128 * 64];
  __shared__ __align__(16) ushort Bs[2][64 * 64];
  const int tid = threadIdx.x;
  const int lane = tid & 63;
  const int quad = lane >> 4;
  const int c = lane & 15;
  const int wv = tid >> 6;          // 0..3
  const int wm = (wv & 1) * 64;
  const int wn = (wv >> 1) * 32;

  // XCD-aware swizzle: each XCD gets 4 contiguous m-rows x all n-tiles.
  const int gx = gridDim.x, gy = gridDim.y;
  const int lid = blockIdx.y * gx + blockIdx.x;
  const int xcd = lid & 7;
  const int idx = lid >> 3;
  const int mrow = xcd * (gy >> 3) + idx / gx;
  const int ncol = idx % gx;
  const size_t m0 = (size_t)mrow * 128;
  const size_t n0 = (size_t)ncol * 64;

  const int srow = lane >> 3;             // row within 8-row slab
  const int sck = (lane & 7) ^ srow;      // swizzled chunk (k) within row

  ffrag zero = {0.f, 0.f, 0.f, 0.f};
  ffrag acc[4][2];
  #pragma unroll
  for (int mt = 0; mt < 4; ++mt)
    #pragma unroll
    for (int nt = 0; nt < 2; ++nt) acc[mt][nt] = zero;

  const int NK = K >> 6;
  #pragma unroll
  for (int i = 0; i < 4; ++i) {
    int ia = wv * 4 + i;
    gl_lds16(&A[(m0 + ia * 8 + srow) * (size_t)K + sck * 8], &As[0][ia * 512]);
  }
  #pragma unroll
  for (int i = 0; i < 2; ++i) {
    int ib = wv * 2 + i;
    gl_lds16(&Bt[(n0 + ib * 8 + srow) * (size_t)K + sck * 8], &Bs[0][ib * 512]);
  }
  __syncthreads();

  for (int ki = 0; ki < NK; ++ki) {
    const int buf = ki & 1;
    if (ki + 1 < NK) {
      int k0 = (ki + 1) << 6;
      #pragma unroll
      for (int i = 0; i < 4; ++i) {
        int ia = wv * 4 + i;
        gl_lds16(&A[(m0 + ia * 8 + srow) * (size_t)K + k0 + sck * 8],
                 &As[buf ^ 1][ia * 512]);
      }
      #pragma unroll
      for (int i = 0; i < 2; ++i) {
        int ib = wv * 2 + i;
        gl_lds16(&Bt[(n0 + ib * 8 + srow) * (size_t)K + k0 + sck * 8],
                 &Bs[buf ^ 1][ib * 512]);
      }
    }
    #pragma unroll
    for (int ks = 0; ks < 2; ++ks) {
      bfrag af[4], bf[2];
      #pragma unroll
      for (int mt = 0; mt < 4; ++mt) {
        int ra = wm + mt * 16 + c;
        af[mt] = *(const bfrag*)&As[buf][(ra * 8 + ((ks * 4 + quad) ^ (ra & 7))) * 8];
      }
      #pragma unroll
      for (int nt = 0; nt < 2; ++nt) {
        int rb = wn + nt * 16 + c;
        bf[nt] = *(const bfrag*)&Bs[buf][(rb * 8 + ((ks * 4 + quad) ^ (rb & 7))) * 8];
      }
      #pragma unroll
      for (int mt = 0; mt < 4; ++mt)
        #pragma unroll
        for (int nt = 0; nt < 2; ++nt)
          acc[mt][nt] = MFMA32(af[mt], bf[nt], acc[mt][nt]);
    }
    __syncthreads();
  }

  #pragma unroll
  for (int nt = 0; nt < 2; ++nt) {
    const int colb = (int)n0 + wn + nt * 16;  // multiple of 16
    if (QKV) {
      if (colb < 1024) {         // Q block (pre-scaled bf16)
        float bb = bias0[colb + c];
        ushort* dst = (ushort*)O1 + colb;
        #pragma unroll
        for (int mt = 0; mt < 4; ++mt)
          #pragma unroll
          for (int r = 0; r < 4; ++r) {
            size_t row = m0 + wm + mt * 16 + quad * 4 + r;
            dst[row * 1024 + c] = f2bf((acc[mt][nt][r] + bb) * qscale);
          }
      } else if (colb < 1088) {  // K block -> Kb [4096 x 64]
        float bb = bias1[colb - 1024 + c];
        ushort* dst = Kb + (colb - 1024);
        #pragma unroll
        for (int mt = 0; mt < 4; ++mt)
          #pragma unroll
          for (int r = 0; r < 4; ++r) {
            size_t row = m0 + wm + mt * 16 + quad * 4 + r;
            dst[row * 64 + c] = f2bf(acc[mt][nt][r] + bb);
          }
      } else {                   // V block -> VT permuted [B][64][S]
        int d = colb - 1088 + c;
        float bb = bias2[colb - 1088 + c];
        int bidx = (int)(m0 >> 11);
        ushort* dstv = VTb + ((size_t)(bidx * 64 + d)) * SS;
        #pragma unroll
        for (int mt = 0; mt < 4; ++mt) {
          int sb = (int)(m0 & 2047) + wm + mt * 16 + quad * 4;  // mult of 4
          // PV-permuted position within the 32-key block (4 consecutive)
          int col = (sb & ~31) + ((sb >> 2) & 3) * 8 + ((sb >> 4) & 1) * 4;
          uint2v u;
          u.x = pack_bf2(acc[mt][nt][0] + bb, acc[mt][nt][1] + bb);
          u.y = pack_bf2(acc[mt][nt][2] + bb, acc[mt][nt][3] + bb);
          *(uint2v*)&dstv[col] = u;
        }
      }
    } else {
      float bb = bias0[colb + c];
      float* dst = (float*)O1;
      #pragma unroll
      for (int mt = 0; mt < 4; ++mt)
        #pragma unroll
        for (int r = 0; r < 4; ++r) {
          size_t row = m0 + wm + mt * 16 + quad * 4 + r;
          dst[row * (size_t)N + colb + c] = acc[mt][nt][r] + bb;
        }
    }
  }
}

// -------------------------------------------------------------------------
// MQA attention v15 (session-best: ~47-50 us, conflicts 0, VGPR 56).
// v12 structure + PV via K=32 MFMA on permuted keys: two 16-key QK^T
// tiles' S^T fragments concatenate into a 16x16x32 B-frag (k = quad*8+j).
// Per 64-key iter: QK 16 MFMA32 + PV 16 MFMA32 + 4 lsum MFMA32; V reads
// 8 b128; all staging via gl_lds16 DMA (linear dest, chunk-swizzled
// GLOBAL source: chunk' = chunk ^ (d&7), <=2-way on read = free).
// Block = 8 waves (512 thr), 128 q; waves 0-3 keys [0,1024), waves 4-7
// keys [1024,2048); each wave owns 32 q (2 q-tiles). 512 blocks.
// Combine halves via retired LDS; normalize by 1/(ls_lo+ls_hi).
// -------------------------------------------------------------------------
__global__ __launch_bounds__(512) void mqa_attn15(
    const ushort* __restrict__ Q, const ushort* __restrict__ Kg,
    const ushort* __restrict__ VT, ushort* __restrict__ A2) {
  __shared__ __align__(16) ushort Kt[2][2][4096];  // [half][buf][64k x 64d]
  __shared__ __align__(16) ushort Vt[2][2][4096];  // [half][buf][64d x 64pos, chunk-swz]
  const int tid = threadIdx.x;
  const int lane = tid & 63;
  const int quad = lane >> 4;
  const int c = lane & 15;
  const int wv = tid >> 6;        // 0..7
  const int half = wv >> 2;       // 0: keys [0,1024), 1: [1024,2048)
  const int lw = wv & 3;          // wave-within-half, owns q-tiles lw*2+{0,1}
  const int bid = blockIdx.x;     // [0, 512)
  const int b = bid >> 8;
  const int r = bid & 255;
  const int h = r >> 4;           // 16 blocks per head
  const int s0 = (r & 15) << 7;   // 128 queries per block

  const int srow = lane >> 3;            // row within 8-row slab
  const int sck = (lane & 7) ^ srow;     // swizzled chunk within row (K staging)

  ffrag zero = {0.f, 0.f, 0.f, 0.f};
  bfrag ones8;
  #pragma unroll
  for (int i = 0; i < 8; ++i) ones8[i] = (short)16256;  // bf16 1.0

  // Q b-frags: 2 q-tiles x 2 d-halves, held for the whole key loop
  bfrag aq[2][2];
  #pragma unroll
  for (int mt = 0; mt < 2; ++mt) {
    const ushort* qp =
        Q + ((size_t)(b * SS) + s0 + lw * 32 + mt * 16 + c) * EE + h * 64 + quad * 8;
    aq[mt][0] = *(const bfrag*)qp;
    aq[mt][1] = *(const bfrag*)(qp + 32);
  }

  ffrag o[2][4];   // O^T accum: [q-tile][d-tile]
  #pragma unroll
  for (int mt = 0; mt < 2; ++mt)
    #pragma unroll
    for (int nt = 0; nt < 4; ++nt) o[mt][nt] = zero;
  ffrag ls[2] = {zero, zero};

  const int koff = half << 10;    // key offset of this half
  const ushort* Kbase = Kg + (size_t)b * SS * 64;
  const ushort* Vbase = VT + (size_t)b * 64 * SS;
  const int i0 = lw * 2, i1 = lw * 2 + 1;
  const int r0 = i0 * 8 + srow, r1 = i1 * 8 + srow;  // key-rows staged (K)

  // V DMA geometry: lane -> (row-in-slab = lane>>3, chunk = lane&7);
  // global source pre-swizzled: chunk' = chunk ^ (d&7); dest linear.
  const int vd0 = lw * 16 + (lane >> 3);       // d row, DMA 0
  const int vd1 = vd0 + 8;                     // d row, DMA 1
  const ushort* vsrc0 = Vbase + (size_t)vd0 * SS + (((lane & 7) ^ (vd0 & 7)) * 8);
  const ushort* vsrc1 = Vbase + (size_t)vd1 * SS + (((lane & 7) ^ (vd1 & 7)) * 8);

  // ---- prologue: stage tile 0 (K + V all via DMA)
  gl_lds16(Kbase + (size_t)(koff + r0) * 64 + sck * 8, &Kt[half][0][i0 * 512]);
  gl_lds16(Kbase + (size_t)(koff + r1) * 64 + sck * 8, &Kt[half][0][i1 * 512]);
  gl_lds16(vsrc0 + koff, &Vt[half][0][(lw * 16) * 64]);
  gl_lds16(vsrc1 + koff, &Vt[half][0][(lw * 16 + 8) * 64]);
  __syncthreads();

  for (int it = 0; it < 16; ++it) {
    const int buf = it & 1;
    if (it + 1 < 16) {  // early-issue next K/V tile (all DMA)
      int kb = koff + ((it + 1) << 6);
      gl_lds16(Kbase + (size_t)(kb + r0) * 64 + sck * 8, &Kt[half][buf ^ 1][i0 * 512]);
      gl_lds16(Kbase + (size_t)(kb + r1) * 64 + sck * 8, &Kt[half][buf ^ 1][i1 * 512]);
      gl_lds16(vsrc0 + kb, &Vt[half][buf ^ 1][(lw * 16) * 64]);
      gl_lds16(vsrc1 + kb, &Vt[half][buf ^ 1][(lw * 16 + 8) * 64]);
    }

    #pragma unroll
    for (int p = 0; p < 2; ++p) {     // 32-key pair-tile
      uint2v uu[2][2];                // [a (16-key subtile)][mt]
      #pragma unroll
      for (int a = 0; a < 2; ++a) {
        const int key = (p * 2 + a) * 16 + c;   // A-frag row (key) for S^T
        const int k7 = key & 7;
        bfrag kf0 = *(const bfrag*)&Kt[half][buf][(key * 8 + (quad ^ k7)) * 8];
        bfrag kf1 = *(const bfrag*)&Kt[half][buf][(key * 8 + ((quad + 4) ^ k7)) * 8];
        #pragma unroll
        for (int mt = 0; mt < 2; ++mt) {
          ffrag st = MFMA32(kf0, aq[mt][0], zero);
          st = MFMA32(kf1, aq[mt][1], st);
          // lane holds S^T[key=(2p+a)*16+quad*4+j][q=mt*16+c], j=0..3
          uu[a][mt].x = pack_bf2(__builtin_amdgcn_exp2f(st[0]),
                                 __builtin_amdgcn_exp2f(st[1]));
          uu[a][mt].y = pack_bf2(__builtin_amdgcn_exp2f(st[2]),
                                 __builtin_amdgcn_exp2f(st[3]));
        }
      }
      // concat -> K=32 B-frag: k = quad*8 + (a*4+j) = permuted V position
      bfrag pb8[2];
      #pragma unroll
      for (int mt = 0; mt < 2; ++mt) {
        uint4v w = {uu[0][mt].x, uu[0][mt].y, uu[1][mt].x, uu[1][mt].y};
        pb8[mt] = __builtin_bit_cast(bfrag, w);
      }
      // PV: O^T[d][q] += V^T-frag(K=32) * P-frag(K=32)
      const int ch = p * 4 + quad;    // logical 16B chunk (8 positions)
      #pragma unroll
      for (int nt = 0; nt < 4; ++nt) {
        int d = nt * 16 + c;
        bfrag vf = *(const bfrag*)&Vt[half][buf][d * 64 + ((ch ^ (d & 7)) * 8)];
        #pragma unroll
        for (int mt = 0; mt < 2; ++mt)
          o[mt][nt] = MFMA32(vf, pb8[mt], o[mt][nt]);
      }
      #pragma unroll
      for (int mt = 0; mt < 2; ++mt)
        ls[mt] = MFMA32(ones8, pb8[mt], ls[mt]);
    }
    __syncthreads();
  }

  // ---- combine halves via retired LDS (Kt area: 4 waves x 8 KB; Vt: lsums)
  float* cbuf = (float*)&Kt[0][0][0];
  float* lbuf = (float*)&Vt[0][0][0];
  if (half == 1) {
    float* wb = cbuf + (size_t)lw * 2048;
    #pragma unroll
    for (int mt = 0; mt < 2; ++mt) {
      #pragma unroll
      for (int nt = 0; nt < 4; ++nt)
        *(ffrag*)&wb[(mt * 4 + nt) * 256 + lane * 4] = o[mt][nt];
      lbuf[lw * 128 + mt * 64 + lane] = ls[mt][0];
    }
  }
  __syncthreads();
  if (half == 1) return;

  const float* rb = cbuf + (size_t)lw * 2048;
  #pragma unroll
  for (int mt = 0; mt < 2; ++mt) {
    #pragma unroll
    for (int nt = 0; nt < 4; ++nt) {
      ffrag pp = *(const ffrag*)&rb[(mt * 4 + nt) * 256 + lane * 4];
      o[mt][nt] += pp;
    }
    const float inv = 1.f / (ls[mt][0] + lbuf[lw * 128 + mt * 64 + lane]);
    const int sp = h * 128 + (s0 >> 4) + lw * 2 + mt;
    ushort* orow = A2 + ((size_t)b * SS + sp) * EE;
    #pragma unroll
    for (int nt = 0; nt < 4; ++nt) {
      uint2v u;
      u.x = pack_bf2(o[mt][nt][0] * inv, o[mt][nt][1] * inv);
      u.y = pack_bf2(o[mt][nt][2] * inv, o[mt][nt][3] * inv);
      *(uint2v*)&orow[c * 64 + nt * 16 + quad * 4] = u;
    }
  }
}

extern "C" void kernel_launch(void* const* d_in, const int* in_sizes, int n_in,
                              void* d_out, int out_size, void* d_ws, size_t ws_size,
                              hipStream_t stream) {
  const float* x  = (const float*)d_in[0];
  const float* wq = (const float*)d_in[1];
  const float* bq = (const float*)d_in[2];
  const float* wk = (const float*)d_in[3];
  const float* bk = (const float*)d_in[4];
  const float* wv = (const float*)d_in[5];
  const float* bv = (const float*)d_in[6];
  const float* wo = (const float*)d_in[7];
  const float* bo = (const float*)d_in[8];
  float* out = (float*)d_out;

  // Workspace layout (bytes)
  char* w = (char*)d_ws;
  ushort* xb     = (ushort*)w;  w += (size_t)4096 * 1024 * 2;  // x bf16
  ushort* wqkvT  = (ushort*)w;  w += (size_t)1152 * 1024 * 2;  // [wq|wk|wv]^T
  ushort* woT    = (ushort*)w;  w += (size_t)1024 * 1024 * 2;  // wo^T bf16
  ushort* Qb     = (ushort*)w;  w += (size_t)4096 * 1024 * 2;  // Q' (pre-scaled)
  ushort* Kb     = (ushort*)w;  w += (size_t)4096 * 64 * 2;    // K bf16 [4096x64]
  ushort* VTb    = (ushort*)w;  w += (size_t)BB * 64 * SS * 2; // V^T bf16 (permuted)
  ushort* A2     = (ushort*)w;  w += (size_t)4096 * 1024 * 2;  // attn (scrambled)

  // Prep: x cast + all weight transposes in one launch
  prep<<<6272, 256, 0, stream>>>(x, wq, wk, wv, wo, xb, wqkvT, woT);

  // Fused QKV projection (V written transposed + PV-permuted).
  const float qscale = 0.18033688011112042f;  // log2(e)/8
  gemm_mfma3<true><<<dim3(18, 32), 256, 0, stream>>>(
      xb, wqkvT, bq, bk, bv, Qb, Kb, VTb, 4096, 1152, 1024, qscale);

  // Attention: v15 -- PV via K=32 MFMA on permuted keys, all-DMA staging
  mqa_attn15<<<512, 512, 0, stream>>>(Qb, Kb, VTb, A2);

  // Output projection (fp32 out + bias)
  gemm_mfma3<false><<<dim3(16, 32), 256, 0, stream>>>(
      A2, woT, bo, nullptr, nullptr, out, nullptr, nullptr, 4096, 1024, 1024, 1.0f);
}